// Round 1
// baseline (95.782 us; speedup 1.0000x reference)
//
#include <hip/hip_runtime.h>

// SkewedLossFunction_OneSide: mean(|y_pred - y_true| * exp(gate * |lam|))
//   lam  = y_true/50 - 1        (both branches of the reference collapse to this)
//   gate = 1 iff (y_true - y_pred) and lam have the same (nonzero) sign
//
// N = 8388608 fp32 elements per input -> 64 MiB read, memory-bound reduce.
// Two-pass: blocks write disjoint partials into d_ws (poisoned 0xAA each call,
// so no atomics / no init dependence), then a 1-block kernel finishes in double.

#define N_ELEM   8388608
#define NBLOCKS  2048
#define NTHREADS 256

__device__ __forceinline__ float skew1(float p, float t) {
    float d    = p - t;
    float base = fabsf(d);
    float lam  = __fmaf_rn(t, 0.02f, -1.0f);     // y/50 - 1, in [-1, 1]
    // gate==1 iff sign(t-p)*sign(lam) > 0  <=>  (t-p)*lam > 0
    float g    = ((t - p) * lam > 0.0f) ? fabsf(lam) : 0.0f;
    return base * __expf(g);                     // exponent in [0,1]
}

__global__ __launch_bounds__(NTHREADS) void skew_partial_kernel(
        const float4* __restrict__ yp,
        const float4* __restrict__ yt,
        float* __restrict__ partial) {
    const int tid = threadIdx.x;
    const int gid = blockIdx.x * NTHREADS + tid;
    const int stride = NBLOCKS * NTHREADS;
    const int n4 = N_ELEM / 4;

    float acc = 0.0f;
    for (int i = gid; i < n4; i += stride) {
        float4 p = yp[i];
        float4 t = yt[i];
        acc += skew1(p.x, t.x);
        acc += skew1(p.y, t.y);
        acc += skew1(p.z, t.z);
        acc += skew1(p.w, t.w);
    }

    // wave-64 shuffle reduce
    #pragma unroll
    for (int off = 32; off > 0; off >>= 1)
        acc += __shfl_down(acc, off, 64);

    __shared__ float wsum[NTHREADS / 64];
    if ((tid & 63) == 0) wsum[tid >> 6] = acc;
    __syncthreads();
    if (tid == 0) {
        float s = 0.0f;
        #pragma unroll
        for (int w = 0; w < NTHREADS / 64; ++w) s += wsum[w];
        partial[blockIdx.x] = s;   // plain store: each block owns its slot
    }
}

__global__ __launch_bounds__(256) void skew_final_kernel(
        const float* __restrict__ partial,
        float* __restrict__ out) {
    const int tid = threadIdx.x;
    double acc = 0.0;
    for (int i = tid; i < NBLOCKS; i += 256)
        acc += (double)partial[i];

    #pragma unroll
    for (int off = 32; off > 0; off >>= 1)
        acc += __shfl_down(acc, off, 64);

    __shared__ double wsum[256 / 64];
    if ((tid & 63) == 0) wsum[tid >> 6] = acc;
    __syncthreads();
    if (tid == 0) {
        double s = wsum[0] + wsum[1] + wsum[2] + wsum[3];
        out[0] = (float)(s / (double)N_ELEM);
    }
}

extern "C" void kernel_launch(void* const* d_in, const int* in_sizes, int n_in,
                              void* d_out, int out_size, void* d_ws, size_t ws_size,
                              hipStream_t stream) {
    const float4* y_pred = (const float4*)d_in[0];
    const float4* y_true = (const float4*)d_in[1];
    float* partial = (float*)d_ws;          // NBLOCKS * 4 bytes = 8 KiB
    float* out     = (float*)d_out;

    skew_partial_kernel<<<NBLOCKS, NTHREADS, 0, stream>>>(y_pred, y_true, partial);
    skew_final_kernel<<<1, 256, 0, stream>>>(partial, out);
}